// Round 3
// baseline (307.654 us; speedup 1.0000x reference)
//
#include <hip/hip_runtime.h>
#include <hip/hip_bf16.h>
#include <math.h>

#define B_   4
#define CIN  64
#define P_   1728
#define N_   1729
#define C_   256
#define NH_  8
#define HD_  32
#define M_   (B_*N_)   // 6916 rows
#define NPAD 1792      // 28 * 64

typedef __bf16 bf16x8 __attribute__((ext_vector_type(8)));
typedef __bf16 bf16x4 __attribute__((ext_vector_type(4)));
typedef float  f32x4  __attribute__((ext_vector_type(4)));
typedef float  f32x16 __attribute__((ext_vector_type(16)));

// ---------------------------------------------------------------------------
// Patch embed. One thread per (b, n, c). Writes t fp32.
// ---------------------------------------------------------------------------
__global__ __launch_bounds__(256) void embed2(
    const float* __restrict__ x, const float* __restrict__ Wpe,
    const float* __restrict__ bpe, const float* __restrict__ cls,
    float* __restrict__ t)
{
    int idx = blockIdx.x*256 + threadIdx.x;        // [0, B*N*C)
    int c   = idx & 255;
    int n   = (idx >> 8) % N_;
    int b   = idx / (N_*256);
    if (n == 0) { t[idx] = cls[c]; return; }
    int p = n - 1;
    float acc = bpe[c];
    for (int ci = 0; ci < CIN; ++ci)
        acc += x[(size_t)(b*CIN + ci)*P_ + p] * Wpe[ci*C_ + c];
    t[idx] = acc;
}

// ---------------------------------------------------------------------------
// ln4: LayerNorm, 4 rows/block (one wave each), float4 in, bf16x4 out.
// ---------------------------------------------------------------------------
__global__ __launch_bounds__(256) void ln4(
    const float* __restrict__ in, __bf16* __restrict__ out,
    const float* __restrict__ g, const float* __restrict__ bb)
{
    int wv = threadIdx.x >> 6, lane = threadIdx.x & 63;
    size_t row = (size_t)blockIdx.x*4 + wv;
    float4 v = *(const float4*)&in[row*C_ + lane*4];
    float s1 = (v.x+v.y)+(v.z+v.w);
    float s2 = (v.x*v.x+v.y*v.y)+(v.z*v.z+v.w*v.w);
    #pragma unroll
    for (int off = 32; off >= 1; off >>= 1) {
        s1 += __shfl_xor(s1, off);
        s2 += __shfl_xor(s2, off);
    }
    float mean = s1*(1.0f/C_);
    float var  = fmaxf(s2*(1.0f/C_) - mean*mean, 0.0f);
    float rstd = rsqrtf(var + 1e-5f);
    float4 gg = *(const float4*)&g[lane*4];
    float4 bv = *(const float4*)&bb[lane*4];
    bf16x4 r;
    r[0] = (__bf16)((v.x-mean)*rstd*gg.x + bv.x);
    r[1] = (__bf16)((v.y-mean)*rstd*gg.y + bv.y);
    r[2] = (__bf16)((v.z-mean)*rstd*gg.z + bv.z);
    r[3] = (__bf16)((v.w-mean)*rstd*gg.w + bv.w);
    *(bf16x4*)&out[row*C_ + lane*4] = r;
}

// ln4f: final norm — fp32 out + cls extraction.
__global__ __launch_bounds__(256) void ln4f(
    const float* __restrict__ in, float* __restrict__ out,
    const float* __restrict__ g, const float* __restrict__ bb,
    float* __restrict__ cls_out)
{
    int wv = threadIdx.x >> 6, lane = threadIdx.x & 63;
    size_t row = (size_t)blockIdx.x*4 + wv;
    float4 v = *(const float4*)&in[row*C_ + lane*4];
    float s1 = (v.x+v.y)+(v.z+v.w);
    float s2 = (v.x*v.x+v.y*v.y)+(v.z*v.z+v.w*v.w);
    #pragma unroll
    for (int off = 32; off >= 1; off >>= 1) {
        s1 += __shfl_xor(s1, off);
        s2 += __shfl_xor(s2, off);
    }
    float mean = s1*(1.0f/C_);
    float var  = fmaxf(s2*(1.0f/C_) - mean*mean, 0.0f);
    float rstd = rsqrtf(var + 1e-5f);
    float4 gg = *(const float4*)&g[lane*4];
    float4 bv = *(const float4*)&bb[lane*4];
    float4 r;
    r.x = (v.x-mean)*rstd*gg.x + bv.x;
    r.y = (v.y-mean)*rstd*gg.y + bv.y;
    r.z = (v.z-mean)*rstd*gg.z + bv.z;
    r.w = (v.w-mean)*rstd*gg.w + bv.w;
    *(float4*)&out[row*C_ + lane*4] = r;
    if ((row % N_) == 0)
        *(float4*)&cls_out[(row / N_)*C_ + lane*4] = r;
}

// ---------------------------------------------------------------------------
// wprep2: all 8 weight matrices -> bf16 W^T[n][k] in one launch.
// ---------------------------------------------------------------------------
__global__ __launch_bounds__(256) void wprep2(
    const float* __restrict__ Wqkv, const float* __restrict__ Wproj,
    const float* __restrict__ W1,   const float* __restrict__ W2,
    __bf16* __restrict__ wT)
{
    int z = blockIdx.z, which = z >> 1, layer = z & 1;
    const float* src; __bf16* dst; int NC;
    if (which == 0) {
        src = Wqkv + (size_t)layer*C_*768;
        dst = wT   + (size_t)layer*768*256;
        NC  = 768;
    } else {
        NC = 256;
        const float* b3 = (which == 1) ? Wproj : (which == 2) ? W1 : W2;
        src = b3 + (size_t)layer*65536;
        dst = wT + 2*768*256 + (size_t)((which-1)*2 + layer)*65536;
    }
    int n0 = blockIdx.x*32; if (n0 >= NC) return;
    int k0 = blockIdx.y*32;
    __shared__ float tile[32][33];
    int c = threadIdx.x & 31, r = threadIdx.x >> 5;
    for (int rr = r; rr < 32; rr += 8)
        tile[rr][c] = src[(size_t)(k0+rr)*NC + n0 + c];
    __syncthreads();
    for (int rr = r; rr < 32; rr += 8)
        dst[(size_t)(n0+rr)*256 + k0 + c] = (__bf16)tile[c][rr];
}

// ---------------------------------------------------------------------------
// padzero: zero kB/vB pad rows (n in [N_, NPAD)) so attention needs no
// masking: pad keys add exp2(0)=1 to l (subtracted as constant 63) and 0 to O.
// ---------------------------------------------------------------------------
__global__ __launch_bounds__(256) void padzero(
    __bf16* __restrict__ kB, __bf16* __restrict__ vB)
{
    int idx = blockIdx.x*256 + threadIdx.x;     // over 32*63*32 = 64512
    if (idx >= 32*63*32) return;
    int d  = idx & 31;
    int n  = (idx >> 5) % 63 + N_;
    int bh = idx / (63*32);
    kB[((size_t)bh*NPAD + n)*32 + d] = (__bf16)0.f;
    vB[((size_t)bh*32 + d)*NPAD + n] = (__bf16)0.f;
}

// ---------------------------------------------------------------------------
// gemm4: double-buffered LDS, ONE __syncthreads per k-step placed AFTER the
// MFMA phase so the compiler's vmcnt(0) (before next-buffer ds_write) lands
// after the compute -> global-load latency hidden.
// ---------------------------------------------------------------------------
template<int NC, bool ADD, bool GELU, bool BIAS, bool OUTBF>
__global__ __launch_bounds__(256) void gemm4(
    const __bf16* __restrict__ A, const __bf16* __restrict__ Wt,
    const float* __restrict__ bias, float* __restrict__ outF,
    __bf16* __restrict__ outB)
{
    __shared__ __align__(16) __bf16 As[2][64*64];
    __shared__ __align__(16) __bf16 Bs[2][64*64];
    int r0 = blockIdx.x*64, c0 = blockIdx.y*64;
    int tid = threadIdx.x;
    int wv = tid >> 6, lane = tid & 63, quad = lane >> 4, mn = lane & 15;
    int sr = tid >> 2, sc = tid & 3;
    int ga = r0 + sr; if (ga >= M_) ga = M_ - 1;

    f32x4 acc[4];
    #pragma unroll
    for (int ct = 0; ct < 4; ++ct)
        #pragma unroll
        for (int rr = 0; rr < 4; ++rr) acc[ct][rr] = 0.f;

    bf16x8 ra0, ra1, rb0, rb1;
#define GLOAD(KC) do {                                                   \
        ra0 = *(const bf16x8*)&A[(size_t)ga*256 + (KC)*64 + sc*8];       \
        ra1 = *(const bf16x8*)&A[(size_t)ga*256 + (KC)*64 + sc*8 + 32];  \
        rb0 = *(const bf16x8*)&Wt[(size_t)(c0+sr)*256 + (KC)*64 + sc*8]; \
        rb1 = *(const bf16x8*)&Wt[(size_t)(c0+sr)*256 + (KC)*64 + sc*8 + 32]; \
    } while (0)
#define SSTORE(BUF) do {                                                 \
        *(bf16x8*)&As[BUF][sr*64 + ((sc ^ (sr & 7))*8)]       = ra0;     \
        *(bf16x8*)&As[BUF][sr*64 + (((sc+4) ^ (sr & 7))*8)]   = ra1;     \
        *(bf16x8*)&Bs[BUF][sr*64 + ((sc ^ (sr & 7))*8)]       = rb0;     \
        *(bf16x8*)&Bs[BUF][sr*64 + (((sc+4) ^ (sr & 7))*8)]   = rb1;     \
    } while (0)

    GLOAD(0);
    SSTORE(0);
    __syncthreads();

    for (int kc = 0; kc < 4; ++kc) {
        int cur = kc & 1;
        if (kc < 3) GLOAD(kc+1);
        __builtin_amdgcn_sched_barrier(0);   // pin prefetch issue before compute

        #pragma unroll
        for (int h = 0; h < 2; ++h) {
            bf16x8 a = *(const bf16x8*)&As[cur][(wv*16 + mn)*64 + (((h*4+quad) ^ (mn & 7))*8)];
            #pragma unroll
            for (int ct = 0; ct < 4; ++ct) {
                bf16x8 b = *(const bf16x8*)&Bs[cur][(ct*16 + mn)*64 + (((h*4+quad) ^ (mn & 7))*8)];
                acc[ct] = __builtin_amdgcn_mfma_f32_16x16x32_bf16(a, b, acc[ct], 0, 0, 0);
            }
        }

        if (kc < 3) {
            SSTORE(cur^1);     // vmcnt(0) lands here, after the MFMA phase
            __syncthreads();
        }
    }
#undef GLOAD
#undef SSTORE

    #pragma unroll
    for (int ct = 0; ct < 4; ++ct) {
        int col = c0 + ct*16 + mn;
        #pragma unroll
        for (int rr = 0; rr < 4; ++rr) {
            int row = r0 + wv*16 + quad*4 + rr;
            if (row >= M_) continue;
            float val = acc[ct][rr];
            if (BIAS) val += bias[col];
            if (GELU) val = 0.5f*val*(1.f + erff(val*0.70710678118654752f));
            size_t oi = (size_t)row*NC + col;
            if (OUTBF) outB[oi] = (__bf16)val;
            else if (ADD) outF[oi] += val;
            else outF[oi] = val;
        }
    }
}

// ---------------------------------------------------------------------------
// gemm_qkv4: same pipelined core; epilogue packs qB (scaled by
// log2e/sqrt(hd) so attention can use raw v_exp_f32 = 2^x), kB, vB^T.
// ---------------------------------------------------------------------------
__global__ __launch_bounds__(256) void gemm_qkv4(
    const __bf16* __restrict__ A, const __bf16* __restrict__ Wt,
    __bf16* __restrict__ qB, __bf16* __restrict__ kB, __bf16* __restrict__ vB)
{
    __shared__ __align__(16) __bf16 As[2][64*64];
    __shared__ __align__(16) __bf16 Bs[2][64*64];
    int r0 = blockIdx.x*64, c0 = blockIdx.y*64;
    int tid = threadIdx.x;
    int wv = tid >> 6, lane = tid & 63, quad = lane >> 4, mn = lane & 15;
    int sr = tid >> 2, sc = tid & 3;
    int ga = r0 + sr; if (ga >= M_) ga = M_ - 1;

    f32x4 acc[4];
    #pragma unroll
    for (int ct = 0; ct < 4; ++ct)
        #pragma unroll
        for (int rr = 0; rr < 4; ++rr) acc[ct][rr] = 0.f;

    bf16x8 ra0, ra1, rb0, rb1;
#define GLOAD(KC) do {                                                   \
        ra0 = *(const bf16x8*)&A[(size_t)ga*256 + (KC)*64 + sc*8];       \
        ra1 = *(const bf16x8*)&A[(size_t)ga*256 + (KC)*64 + sc*8 + 32];  \
        rb0 = *(const bf16x8*)&Wt[(size_t)(c0+sr)*256 + (KC)*64 + sc*8]; \
        rb1 = *(const bf16x8*)&Wt[(size_t)(c0+sr)*256 + (KC)*64 + sc*8 + 32]; \
    } while (0)
#define SSTORE(BUF) do {                                                 \
        *(bf16x8*)&As[BUF][sr*64 + ((sc ^ (sr & 7))*8)]       = ra0;     \
        *(bf16x8*)&As[BUF][sr*64 + (((sc+4) ^ (sr & 7))*8)]   = ra1;     \
        *(bf16x8*)&Bs[BUF][sr*64 + ((sc ^ (sr & 7))*8)]       = rb0;     \
        *(bf16x8*)&Bs[BUF][sr*64 + (((sc+4) ^ (sr & 7))*8)]   = rb1;     \
    } while (0)

    GLOAD(0);
    SSTORE(0);
    __syncthreads();

    for (int kc = 0; kc < 4; ++kc) {
        int cur = kc & 1;
        if (kc < 3) GLOAD(kc+1);
        __builtin_amdgcn_sched_barrier(0);

        #pragma unroll
        for (int h = 0; h < 2; ++h) {
            bf16x8 a = *(const bf16x8*)&As[cur][(wv*16 + mn)*64 + (((h*4+quad) ^ (mn & 7))*8)];
            #pragma unroll
            for (int ct = 0; ct < 4; ++ct) {
                bf16x8 b = *(const bf16x8*)&Bs[cur][(ct*16 + mn)*64 + (((h*4+quad) ^ (mn & 7))*8)];
                acc[ct] = __builtin_amdgcn_mfma_f32_16x16x32_bf16(a, b, acc[ct], 0, 0, 0);
            }
        }

        if (kc < 3) {
            SSTORE(cur^1);
            __syncthreads();
        }
    }
#undef GLOAD
#undef SSTORE

    const float scale = 0.2550348727f;   // log2(e)/sqrt(32)
    #pragma unroll
    for (int ct = 0; ct < 4; ++ct) {
        int col = c0 + ct*16 + mn;
        #pragma unroll
        for (int rr = 0; rr < 4; ++rr) {
            int row = r0 + wv*16 + quad*4 + rr;
            if (row >= M_) continue;
            int b = row / N_, n = row - b*N_;
            float val = acc[ct][rr];
            if (col < 256) {
                int h = col >> 5, dd = col & 31;
                qB[((size_t)(b*NH_+h)*NPAD + n)*32 + dd] = (__bf16)(val*scale);
            } else if (col < 512) {
                int h = (col-256) >> 5, dd = col & 31;
                kB[((size_t)(b*NH_+h)*NPAD + n)*32 + dd] = (__bf16)val;
            } else {
                int h = (col-512) >> 5, dd = col & 31;
                vB[((size_t)(b*NH_+h)*32 + dd)*NPAD + n] = (__bf16)val;
            }
        }
    }
}

// ---------------------------------------------------------------------------
// attn14: ZERO-LDS attention. K/V per head are L2-resident (229 KB) and both
// operands are directly per-lane addressable in global memory (K row-major,
// V transposed), so the global->LDS->fragment round trip plus its per-tile
// barrier drain -- invariant across attn11/12/13, all ~41-45 us -- is pure
// overhead (Common-mistake #7). No __shared__, no __syncthreads anywhere:
// 16 global_load_dwordx4 per tile, deeply pipelinable across kg and tiles.
// Softmax stays fully in-register (swapped QK^T, cvt_pk+permlane32_swap).
// ---------------------------------------------------------------------------
__device__ __forceinline__ float fexp2(float x) {
    float r; asm("v_exp_f32 %0, %1" : "=v"(r) : "v"(x)); return r;
}
__device__ __forceinline__ unsigned cvtpk_bf16(float lo, float hi) {
    unsigned r;
    asm("v_cvt_pk_bf16_f32 %0, %1, %2" : "=v"(r) : "v"(lo), "v"(hi));
    return r;
}

__global__ __launch_bounds__(128) void attn14(
    const __bf16* __restrict__ qB, const __bf16* __restrict__ kB,
    const __bf16* __restrict__ vB, __bf16* __restrict__ o)
{
    int bh = blockIdx.x, b = bh >> 3, h = bh & 7;
    int q0 = blockIdx.y * 64;
    int tid = threadIdx.x;
    int wv = tid >> 6, lane = tid & 63, lo5 = lane & 31, hi = lane >> 5;

    const __bf16* kbase = kB + (size_t)bh*NPAD*32;
    const __bf16* vbase = vB + (size_t)bh*32*NPAD;

    const __bf16* qrow = qB + ((size_t)bh*NPAD + q0 + wv*32 + lo5)*32 + hi*8;
    bf16x8 qf0 = *(const bf16x8*)(qrow);        // d = hi*8 .. +7
    bf16x8 qf1 = *(const bf16x8*)(qrow + 16);   // d = 16+hi*8 .. +7

    f32x16 oaccA, oaccB;
    #pragma unroll
    for (int r = 0; r < 16; ++r) { oaccA[r] = 0.f; oaccB[r] = 0.f; }
    float lsum = 0.f;

    // Per-lane fragment addresses (constant across tiles except +128 keys).
    const __bf16* kp = kbase + (size_t)lo5*32 + hi*8;       // + kg*1024 + t*4096
    const __bf16* vp = vbase + (size_t)lo5*NPAD + hi*8;     // + kg*32   + t*128

    for (int t = 0; t < 14; ++t) {
        // ---- issue all 16 fragment loads for this tile ----
        bf16x8 kf0[4], kf1[4], vf0[4], vf1[4];
        #pragma unroll
        for (int kg = 0; kg < 4; ++kg) {
            const __bf16* kpp = kp + (size_t)t*128*32 + kg*32*32;
            kf0[kg] = *(const bf16x8*)(kpp);
            kf1[kg] = *(const bf16x8*)(kpp + 16);
            const __bf16* vpp = vp + (size_t)t*128 + kg*32;
            vf0[kg] = *(const bf16x8*)(vpp);
            vf1[kg] = *(const bf16x8*)(vpp + 16);
        }

        // ---- per-kg: QK^T -> exp2 -> pack -> PV, all in registers ----
        #pragma unroll
        for (int kg = 0; kg < 4; ++kg) {
            f32x16 s;
            #pragma unroll
            for (int r = 0; r < 16; ++r) s[r] = 0.f;
            __builtin_amdgcn_s_setprio(1);
            s = __builtin_amdgcn_mfma_f32_32x32x16_bf16(kf0[kg], qf0, s, 0, 0, 0);
            s = __builtin_amdgcn_mfma_f32_32x32x16_bf16(kf1[kg], qf1, s, 0, 0, 0);
            __builtin_amdgcn_s_setprio(0);

            // lane holds P[q=lo5][key = t*128 + kg*32 + (r&3)+8*(r>>2)+4*hi]
            float p[16];
            #pragma unroll
            for (int r = 0; r < 16; ++r) p[r] = fexp2(s[r]);
            float l0 = 0.f, l1 = 0.f;
            #pragma unroll
            for (int r = 0; r < 8; ++r) { l0 += p[r]; l1 += p[r+8]; }
            lsum += l0 + l1;

            unsigned a0 = cvtpk_bf16(p[0],  p[1]),  a1 = cvtpk_bf16(p[2],  p[3]);
            unsigned b0 = cvtpk_bf16(p[4],  p[5]),  b1 = cvtpk_bf16(p[6],  p[7]);
            unsigned c0 = cvtpk_bf16(p[8],  p[9]),  c1 = cvtpk_bf16(p[10], p[11]);
            unsigned d0 = cvtpk_bf16(p[12], p[13]), d1 = cvtpk_bf16(p[14], p[15]);
            asm("v_permlane32_swap_b32 %0, %1" : "+v"(a0), "+v"(b0));
            asm("v_permlane32_swap_b32 %0, %1" : "+v"(a1), "+v"(b1));
            asm("v_permlane32_swap_b32 %0, %1" : "+v"(c0), "+v"(d0));
            asm("v_permlane32_swap_b32 %0, %1" : "+v"(c1), "+v"(d1));
            union { bf16x8 v; unsigned u[4]; } f0, f1;
            f0.u[0] = a0; f0.u[1] = a1; f0.u[2] = b0; f0.u[3] = b1;
            f1.u[0] = c0; f1.u[1] = c1; f1.u[2] = d0; f1.u[3] = d1;

            __builtin_amdgcn_s_setprio(1);
            if (kg & 1) {
                oaccB = __builtin_amdgcn_mfma_f32_32x32x16_bf16(f0.v, vf0[kg], oaccB, 0, 0, 0);
                oaccB = __builtin_amdgcn_mfma_f32_32x32x16_bf16(f1.v, vf1[kg], oaccB, 0, 0, 0);
            } else {
                oaccA = __builtin_amdgcn_mfma_f32_32x32x16_bf16(f0.v, vf0[kg], oaccA, 0, 0, 0);
                oaccA = __builtin_amdgcn_mfma_f32_32x32x16_bf16(f1.v, vf1[kg], oaccA, 0, 0, 0);
            }
            __builtin_amdgcn_s_setprio(0);
        }
    }

    // l(q): halves hold disjoint key subsets -> combine; subtract 63 pads.
    lsum += __shfl_xor(lsum, 32);
    float inv = 1.0f / (lsum - 63.0f);       // lane lo5 holds inv for its q

    #pragma unroll
    for (int r = 0; r < 16; ++r) {
        float oa = oaccA[r] + oaccB[r];
        int qrw = (r & 3) + 8*(r >> 2) + 4*hi;
        float li = __shfl(inv, qrw);
        int q = q0 + wv*32 + qrw;
        if (q < N_)
            o[((size_t)b*N_ + q)*C_ + h*HD_ + lo5] = (__bf16)(oa * li);
    }
}

// ---------------------------------------------------------------------------
// feat3: LDS 32x32 tile transpose (fp32). grid (54, 8, 4).
// ---------------------------------------------------------------------------
__global__ __launch_bounds__(256) void feat3(
    const float* __restrict__ y, float* __restrict__ outf)
{
    __shared__ float tl[32][33];
    int p0 = blockIdx.x*32, c0 = blockIdx.y*32, b = blockIdx.z;
    int cc = threadIdx.x & 31, rr = threadIdx.x >> 5;
    for (int i = rr; i < 32; i += 8)
        tl[i][cc] = y[((size_t)(b*N_) + 1 + p0 + i)*C_ + c0 + cc];
    __syncthreads();
    for (int i = rr; i < 32; i += 8)
        outf[((size_t)(b*C_) + c0 + i)*P_ + p0 + cc] = tl[cc][i];
}

// ---------------------------------------------------------------------------
extern "C" void kernel_launch(void* const* d_in, const int* in_sizes, int n_in,
                              void* d_out, int out_size, void* d_ws, size_t ws_size,
                              hipStream_t stream)
{
    const float* x        = (const float*)d_in[0];
    const float* W_pe     = (const float*)d_in[1];
    const float* b_pe     = (const float*)d_in[2];
    const float* cls_tok  = (const float*)d_in[3];
    const float* ln1_g    = (const float*)d_in[4];
    const float* ln1_b    = (const float*)d_in[5];
    const float* Wqkv     = (const float*)d_in[6];
    const float* Wproj    = (const float*)d_in[7];
    const float* bproj    = (const float*)d_in[8];
    const float* ln2_g    = (const float*)d_in[9];
    const float* ln2_b    = (const float*)d_in[10];
    const float* W1       = (const float*)d_in[11];
    const float* b1       = (const float*)d_in[12];
    const float* W2       = (const float*)d_in[13];
    const float* b2       = (const float*)d_in[14];
    const float* normf_g  = (const float*)d_in[15];
    const float* normf_b  = (const float*)d_in[16];

    const size_t MC = (size_t)M_*C_;    // 1,770,496
    float*  ws  = (float*)d_ws;
    float*  t   = ws;                               // MC fp32
    float*  yf  = ws + MC;                          // MC fp32 (final ln out)
    __bf16* ybf = (__bf16*)(ws + 2*MC);             // MC bf16
    __bf16* hbf = (__bf16*)(ws + 2*MC + MC/2);      // MC bf16
    __bf16* obf = (__bf16*)(ws + 2*MC + MC);        // MC bf16
    __bf16* wT  = (__bf16*)(ws + 2*MC + 3*(MC/2));  // 786432 bf16
    __bf16* qB  = wT + 2*768*256 + 6*256*256;       // [32][NPAD][32]
    __bf16* kB  = qB + (size_t)B_*NH_*NPAD*32;
    __bf16* vB  = kB + (size_t)B_*NH_*NPAD*32;      // [32][32][NPAD]

    __bf16* projT = wT + 2*768*256;
    __bf16* w1T   = projT + 2*256*256;
    __bf16* w2T   = w1T   + 2*256*256;

    float* out_cls  = (float*)d_out;
    float* out_feat = out_cls + B_*C_;

    wprep2<<<dim3(24, 8, 8), 256, 0, stream>>>(Wqkv, Wproj, W1, W2, wT);
    padzero<<<252, 256, 0, stream>>>(kB, vB);
    embed2<<<(B_*N_*C_)/256, 256, 0, stream>>>(x, W_pe, b_pe, cls_tok, t);

    const int GRID_M = (M_ + 63) / 64;   // 109
    for (int i = 0; i < 2; ++i) {
        ln4<<<M_/4, 256, 0, stream>>>(t, ybf, ln1_g + i*C_, ln1_b + i*C_);
        gemm_qkv4<<<dim3(GRID_M, 12), 256, 0, stream>>>(
            ybf, wT + (size_t)i*768*256, qB, kB, vB);
        attn14<<<dim3(32, 28), 128, 0, stream>>>(qB, kB, vB, obf);
        gemm4<256,true,false,true,false><<<dim3(GRID_M, 4), 256, 0, stream>>>(
            obf, projT + (size_t)i*65536, bproj + i*C_, t, nullptr);
        ln4<<<M_/4, 256, 0, stream>>>(t, ybf, ln2_g + i*C_, ln2_b + i*C_);
        gemm4<256,false,true,true,true><<<dim3(GRID_M, 4), 256, 0, stream>>>(
            ybf, w1T + (size_t)i*65536, b1 + i*C_, nullptr, hbf);
        gemm4<256,true,false,true,false><<<dim3(GRID_M, 4), 256, 0, stream>>>(
            hbf, w2T + (size_t)i*65536, b2 + i*C_, t, nullptr);
    }

    ln4f<<<M_/4, 256, 0, stream>>>(t, yf, normf_g, normf_b, out_cls);
    feat3<<<dim3(54, 8, 4), 256, 0, stream>>>(yf, out_feat);
}

// Round 4
// 304.615 us; speedup vs baseline: 1.0100x; 1.0100x over previous
//
#include <hip/hip_runtime.h>
#include <hip/hip_bf16.h>
#include <math.h>

#define B_   4
#define CIN  64
#define P_   1728
#define N_   1729
#define C_   256
#define NH_  8
#define HD_  32
#define M_   (B_*N_)   // 6916 rows
#define NPAD 1792      // 28 * 64

typedef __bf16 bf16x8 __attribute__((ext_vector_type(8)));
typedef __bf16 bf16x4 __attribute__((ext_vector_type(4)));
typedef float  f32x4  __attribute__((ext_vector_type(4)));
typedef float  f32x16 __attribute__((ext_vector_type(16)));

// ---------------------------------------------------------------------------
// Patch embed. One thread per (b, n, c). Writes t fp32.
// ---------------------------------------------------------------------------
__global__ __launch_bounds__(256) void embed2(
    const float* __restrict__ x, const float* __restrict__ Wpe,
    const float* __restrict__ bpe, const float* __restrict__ cls,
    float* __restrict__ t)
{
    int idx = blockIdx.x*256 + threadIdx.x;        // [0, B*N*C)
    int c   = idx & 255;
    int n   = (idx >> 8) % N_;
    int b   = idx / (N_*256);
    if (n == 0) { t[idx] = cls[c]; return; }
    int p = n - 1;
    float acc = bpe[c];
    for (int ci = 0; ci < CIN; ++ci)
        acc += x[(size_t)(b*CIN + ci)*P_ + p] * Wpe[ci*C_ + c];
    t[idx] = acc;
}

// ---------------------------------------------------------------------------
// ln4: LayerNorm, 4 rows/block (one wave each), float4 in, bf16x4 out.
// ---------------------------------------------------------------------------
__global__ __launch_bounds__(256) void ln4(
    const float* __restrict__ in, __bf16* __restrict__ out,
    const float* __restrict__ g, const float* __restrict__ bb)
{
    int wv = threadIdx.x >> 6, lane = threadIdx.x & 63;
    size_t row = (size_t)blockIdx.x*4 + wv;
    float4 v = *(const float4*)&in[row*C_ + lane*4];
    float s1 = (v.x+v.y)+(v.z+v.w);
    float s2 = (v.x*v.x+v.y*v.y)+(v.z*v.z+v.w*v.w);
    #pragma unroll
    for (int off = 32; off >= 1; off >>= 1) {
        s1 += __shfl_xor(s1, off);
        s2 += __shfl_xor(s2, off);
    }
    float mean = s1*(1.0f/C_);
    float var  = fmaxf(s2*(1.0f/C_) - mean*mean, 0.0f);
    float rstd = rsqrtf(var + 1e-5f);
    float4 gg = *(const float4*)&g[lane*4];
    float4 bv = *(const float4*)&bb[lane*4];
    bf16x4 r;
    r[0] = (__bf16)((v.x-mean)*rstd*gg.x + bv.x);
    r[1] = (__bf16)((v.y-mean)*rstd*gg.y + bv.y);
    r[2] = (__bf16)((v.z-mean)*rstd*gg.z + bv.z);
    r[3] = (__bf16)((v.w-mean)*rstd*gg.w + bv.w);
    *(bf16x4*)&out[row*C_ + lane*4] = r;
}

// ln4f: final norm — fp32 out + cls extraction.
__global__ __launch_bounds__(256) void ln4f(
    const float* __restrict__ in, float* __restrict__ out,
    const float* __restrict__ g, const float* __restrict__ bb,
    float* __restrict__ cls_out)
{
    int wv = threadIdx.x >> 6, lane = threadIdx.x & 63;
    size_t row = (size_t)blockIdx.x*4 + wv;
    float4 v = *(const float4*)&in[row*C_ + lane*4];
    float s1 = (v.x+v.y)+(v.z+v.w);
    float s2 = (v.x*v.x+v.y*v.y)+(v.z*v.z+v.w*v.w);
    #pragma unroll
    for (int off = 32; off >= 1; off >>= 1) {
        s1 += __shfl_xor(s1, off);
        s2 += __shfl_xor(s2, off);
    }
    float mean = s1*(1.0f/C_);
    float var  = fmaxf(s2*(1.0f/C_) - mean*mean, 0.0f);
    float rstd = rsqrtf(var + 1e-5f);
    float4 gg = *(const float4*)&g[lane*4];
    float4 bv = *(const float4*)&bb[lane*4];
    float4 r;
    r.x = (v.x-mean)*rstd*gg.x + bv.x;
    r.y = (v.y-mean)*rstd*gg.y + bv.y;
    r.z = (v.z-mean)*rstd*gg.z + bv.z;
    r.w = (v.w-mean)*rstd*gg.w + bv.w;
    *(float4*)&out[row*C_ + lane*4] = r;
    if ((row % N_) == 0)
        *(float4*)&cls_out[(row / N_)*C_ + lane*4] = r;
}

// ---------------------------------------------------------------------------
// wprep2: all 8 weight matrices -> bf16 W^T[n][k] in one launch.
// ---------------------------------------------------------------------------
__global__ __launch_bounds__(256) void wprep2(
    const float* __restrict__ Wqkv, const float* __restrict__ Wproj,
    const float* __restrict__ W1,   const float* __restrict__ W2,
    __bf16* __restrict__ wT)
{
    int z = blockIdx.z, which = z >> 1, layer = z & 1;
    const float* src; __bf16* dst; int NC;
    if (which == 0) {
        src = Wqkv + (size_t)layer*C_*768;
        dst = wT   + (size_t)layer*768*256;
        NC  = 768;
    } else {
        NC = 256;
        const float* b3 = (which == 1) ? Wproj : (which == 2) ? W1 : W2;
        src = b3 + (size_t)layer*65536;
        dst = wT + 2*768*256 + (size_t)((which-1)*2 + layer)*65536;
    }
    int n0 = blockIdx.x*32; if (n0 >= NC) return;
    int k0 = blockIdx.y*32;
    __shared__ float tile[32][33];
    int c = threadIdx.x & 31, r = threadIdx.x >> 5;
    for (int rr = r; rr < 32; rr += 8)
        tile[rr][c] = src[(size_t)(k0+rr)*NC + n0 + c];
    __syncthreads();
    for (int rr = r; rr < 32; rr += 8)
        dst[(size_t)(n0+rr)*256 + k0 + c] = (__bf16)tile[c][rr];
}

// ---------------------------------------------------------------------------
// padzero: zero kB/vB pad rows (n in [N_, NPAD)) so attention needs no
// masking: pad keys add exp2(0)=1 to l (subtracted as constant 63) and 0 to O.
// ---------------------------------------------------------------------------
__global__ __launch_bounds__(256) void padzero(
    __bf16* __restrict__ kB, __bf16* __restrict__ vB)
{
    int idx = blockIdx.x*256 + threadIdx.x;     // over 32*63*32 = 64512
    if (idx >= 32*63*32) return;
    int d  = idx & 31;
    int n  = (idx >> 5) % 63 + N_;
    int bh = idx / (63*32);
    kB[((size_t)bh*NPAD + n)*32 + d] = (__bf16)0.f;
    vB[((size_t)bh*32 + d)*NPAD + n] = (__bf16)0.f;
}

// ---------------------------------------------------------------------------
// gemm4: double-buffered LDS, ONE __syncthreads per k-step placed AFTER the
// MFMA phase so the compiler's vmcnt(0) (before next-buffer ds_write) lands
// after the compute -> global-load latency hidden.
// ---------------------------------------------------------------------------
template<int NC, bool ADD, bool GELU, bool BIAS, bool OUTBF>
__global__ __launch_bounds__(256) void gemm4(
    const __bf16* __restrict__ A, const __bf16* __restrict__ Wt,
    const float* __restrict__ bias, float* __restrict__ outF,
    __bf16* __restrict__ outB)
{
    __shared__ __align__(16) __bf16 As[2][64*64];
    __shared__ __align__(16) __bf16 Bs[2][64*64];
    int r0 = blockIdx.x*64, c0 = blockIdx.y*64;
    int tid = threadIdx.x;
    int wv = tid >> 6, lane = tid & 63, quad = lane >> 4, mn = lane & 15;
    int sr = tid >> 2, sc = tid & 3;
    int ga = r0 + sr; if (ga >= M_) ga = M_ - 1;

    f32x4 acc[4];
    #pragma unroll
    for (int ct = 0; ct < 4; ++ct)
        #pragma unroll
        for (int rr = 0; rr < 4; ++rr) acc[ct][rr] = 0.f;

    bf16x8 ra0, ra1, rb0, rb1;
#define GLOAD(KC) do {                                                   \
        ra0 = *(const bf16x8*)&A[(size_t)ga*256 + (KC)*64 + sc*8];       \
        ra1 = *(const bf16x8*)&A[(size_t)ga*256 + (KC)*64 + sc*8 + 32];  \
        rb0 = *(const bf16x8*)&Wt[(size_t)(c0+sr)*256 + (KC)*64 + sc*8]; \
        rb1 = *(const bf16x8*)&Wt[(size_t)(c0+sr)*256 + (KC)*64 + sc*8 + 32]; \
    } while (0)
#define SSTORE(BUF) do {                                                 \
        *(bf16x8*)&As[BUF][sr*64 + ((sc ^ (sr & 7))*8)]       = ra0;     \
        *(bf16x8*)&As[BUF][sr*64 + (((sc+4) ^ (sr & 7))*8)]   = ra1;     \
        *(bf16x8*)&Bs[BUF][sr*64 + ((sc ^ (sr & 7))*8)]       = rb0;     \
        *(bf16x8*)&Bs[BUF][sr*64 + (((sc+4) ^ (sr & 7))*8)]   = rb1;     \
    } while (0)

    GLOAD(0);
    SSTORE(0);
    __syncthreads();

    for (int kc = 0; kc < 4; ++kc) {
        int cur = kc & 1;
        if (kc < 3) GLOAD(kc+1);
        __builtin_amdgcn_sched_barrier(0);   // pin prefetch issue before compute

        #pragma unroll
        for (int h = 0; h < 2; ++h) {
            bf16x8 a = *(const bf16x8*)&As[cur][(wv*16 + mn)*64 + (((h*4+quad) ^ (mn & 7))*8)];
            #pragma unroll
            for (int ct = 0; ct < 4; ++ct) {
                bf16x8 b = *(const bf16x8*)&Bs[cur][(ct*16 + mn)*64 + (((h*4+quad) ^ (mn & 7))*8)];
                acc[ct] = __builtin_amdgcn_mfma_f32_16x16x32_bf16(a, b, acc[ct], 0, 0, 0);
            }
        }

        if (kc < 3) {
            SSTORE(cur^1);     // vmcnt(0) lands here, after the MFMA phase
            __syncthreads();
        }
    }
#undef GLOAD
#undef SSTORE

    #pragma unroll
    for (int ct = 0; ct < 4; ++ct) {
        int col = c0 + ct*16 + mn;
        #pragma unroll
        for (int rr = 0; rr < 4; ++rr) {
            int row = r0 + wv*16 + quad*4 + rr;
            if (row >= M_) continue;
            float val = acc[ct][rr];
            if (BIAS) val += bias[col];
            if (GELU) val = 0.5f*val*(1.f + erff(val*0.70710678118654752f));
            size_t oi = (size_t)row*NC + col;
            if (OUTBF) outB[oi] = (__bf16)val;
            else if (ADD) outF[oi] += val;
            else outF[oi] = val;
        }
    }
}

// ---------------------------------------------------------------------------
// gemm_qkv4: same pipelined core; epilogue packs qB (scaled by
// log2e/sqrt(hd) so attention can use raw v_exp_f32 = 2^x), kB, vB^T.
// ---------------------------------------------------------------------------
__global__ __launch_bounds__(256) void gemm_qkv4(
    const __bf16* __restrict__ A, const __bf16* __restrict__ Wt,
    __bf16* __restrict__ qB, __bf16* __restrict__ kB, __bf16* __restrict__ vB)
{
    __shared__ __align__(16) __bf16 As[2][64*64];
    __shared__ __align__(16) __bf16 Bs[2][64*64];
    int r0 = blockIdx.x*64, c0 = blockIdx.y*64;
    int tid = threadIdx.x;
    int wv = tid >> 6, lane = tid & 63, quad = lane >> 4, mn = lane & 15;
    int sr = tid >> 2, sc = tid & 3;
    int ga = r0 + sr; if (ga >= M_) ga = M_ - 1;

    f32x4 acc[4];
    #pragma unroll
    for (int ct = 0; ct < 4; ++ct)
        #pragma unroll
        for (int rr = 0; rr < 4; ++rr) acc[ct][rr] = 0.f;

    bf16x8 ra0, ra1, rb0, rb1;
#define GLOAD(KC) do {                                                   \
        ra0 = *(const bf16x8*)&A[(size_t)ga*256 + (KC)*64 + sc*8];       \
        ra1 = *(const bf16x8*)&A[(size_t)ga*256 + (KC)*64 + sc*8 + 32];  \
        rb0 = *(const bf16x8*)&Wt[(size_t)(c0+sr)*256 + (KC)*64 + sc*8]; \
        rb1 = *(const bf16x8*)&Wt[(size_t)(c0+sr)*256 + (KC)*64 + sc*8 + 32]; \
    } while (0)
#define SSTORE(BUF) do {                                                 \
        *(bf16x8*)&As[BUF][sr*64 + ((sc ^ (sr & 7))*8)]       = ra0;     \
        *(bf16x8*)&As[BUF][sr*64 + (((sc+4) ^ (sr & 7))*8)]   = ra1;     \
        *(bf16x8*)&Bs[BUF][sr*64 + ((sc ^ (sr & 7))*8)]       = rb0;     \
        *(bf16x8*)&Bs[BUF][sr*64 + (((sc+4) ^ (sr & 7))*8)]   = rb1;     \
    } while (0)

    GLOAD(0);
    SSTORE(0);
    __syncthreads();

    for (int kc = 0; kc < 4; ++kc) {
        int cur = kc & 1;
        if (kc < 3) GLOAD(kc+1);
        __builtin_amdgcn_sched_barrier(0);

        #pragma unroll
        for (int h = 0; h < 2; ++h) {
            bf16x8 a = *(const bf16x8*)&As[cur][(wv*16 + mn)*64 + (((h*4+quad) ^ (mn & 7))*8)];
            #pragma unroll
            for (int ct = 0; ct < 4; ++ct) {
                bf16x8 b = *(const bf16x8*)&Bs[cur][(ct*16 + mn)*64 + (((h*4+quad) ^ (mn & 7))*8)];
                acc[ct] = __builtin_amdgcn_mfma_f32_16x16x32_bf16(a, b, acc[ct], 0, 0, 0);
            }
        }

        if (kc < 3) {
            SSTORE(cur^1);
            __syncthreads();
        }
    }
#undef GLOAD
#undef SSTORE

    const float scale = 0.2550348727f;   // log2(e)/sqrt(32)
    #pragma unroll
    for (int ct = 0; ct < 4; ++ct) {
        int col = c0 + ct*16 + mn;
        #pragma unroll
        for (int rr = 0; rr < 4; ++rr) {
            int row = r0 + wv*16 + quad*4 + rr;
            if (row >= M_) continue;
            int b = row / N_, n = row - b*N_;
            float val = acc[ct][rr];
            if (col < 256) {
                int h = col >> 5, dd = col & 31;
                qB[((size_t)(b*NH_+h)*NPAD + n)*32 + dd] = (__bf16)(val*scale);
            } else if (col < 512) {
                int h = (col-256) >> 5, dd = col & 31;
                kB[((size_t)(b*NH_+h)*NPAD + n)*32 + dd] = (__bf16)val;
            } else {
                int h = (col-512) >> 5, dd = col & 31;
                vB[((size_t)(b*NH_+h)*32 + dd)*NPAD + n] = (__bf16)val;
            }
        }
    }
}

// ---------------------------------------------------------------------------
// attn15: intra-block split-K flash attention, zero staging LDS, 4 waves.
// Waves {0,1}: keys [0,896). Waves {2,3}: keys [896,1792) (incl 63 zero pads).
// Wave wv owns q rows q0 + (wv&1)*32 .. +31. Doubles waves/SIMD vs attn14
// AND halves each wave's serial key chain (28 kg-steps -> 14 each... per
// split: 28 steps of 32 keys). Flat kg loop with depth-1 register prefetch
// (next step's 4 fragment loads issued before current compute; counted
// vmcnt, no barriers in the loop). Partials combined via 8.5 KB LDS at the
// end: O = O01+O23, l = l01+l23-63 (additive since no max subtraction).
// ---------------------------------------------------------------------------
__device__ __forceinline__ float fexp2(float x) {
    float r; asm("v_exp_f32 %0, %1" : "=v"(r) : "v"(x)); return r;
}
__device__ __forceinline__ unsigned cvtpk_bf16(float lo, float hi) {
    unsigned r;
    asm("v_cvt_pk_bf16_f32 %0, %1, %2" : "=v"(r) : "v"(lo), "v"(hi));
    return r;
}

__global__ __launch_bounds__(256) void attn15(
    const __bf16* __restrict__ qB, const __bf16* __restrict__ kB,
    const __bf16* __restrict__ vB, __bf16* __restrict__ o)
{
    int bh = blockIdx.x, b = bh >> 3, h = bh & 7;
    int q0 = blockIdx.y * 64;
    int tid = threadIdx.x;
    int wv = tid >> 6;
    int qw  = wv & 1;        // which 32-row q-half this wave owns
    int swv = wv >> 1;       // key-split: 0 -> [0,896), 1 -> [896,1792)
    int lane = tid & 63, lo5 = lane & 31, hi = lane >> 5;

    __shared__ float lds_o[2][16][64];   // split-1 partial O   (8 KB)
    __shared__ float lds_l[2][64];       // split-1 partial l   (512 B)

    const __bf16* kbase = kB + (size_t)bh*NPAD*32;
    const __bf16* vbase = vB + (size_t)bh*32*NPAD;

    const __bf16* qrow = qB + ((size_t)bh*NPAD + q0 + qw*32 + lo5)*32 + hi*8;
    bf16x8 qf0 = *(const bf16x8*)(qrow);        // d = hi*8 .. +7
    bf16x8 qf1 = *(const bf16x8*)(qrow + 16);   // d = 16+hi*8 .. +7

    f32x16 oaccA, oaccB;
    #pragma unroll
    for (int r = 0; r < 16; ++r) { oaccA[r] = 0.f; oaccB[r] = 0.f; }
    float lsum = 0.f;

    // Per-lane fragment bases for this key-split (28 steps of 32 keys).
    const __bf16* kp = kbase + (size_t)(swv*896 + lo5)*32 + hi*8;   // + i*1024
    const __bf16* vp = vbase + (size_t)lo5*NPAD + swv*896 + hi*8;   // + i*32

    // depth-1 software pipeline: loads for step i+1 in flight during step i.
    bf16x8 kf0n = *(const bf16x8*)(kp);
    bf16x8 kf1n = *(const bf16x8*)(kp + 16);
    bf16x8 vf0n = *(const bf16x8*)(vp);
    bf16x8 vf1n = *(const bf16x8*)(vp + 16);

    for (int i = 0; i < 28; ++i) {
        bf16x8 kf0 = kf0n, kf1 = kf1n, vf0 = vf0n, vf1 = vf1n;
        if (i < 27) {
            const __bf16* kpp = kp + (size_t)(i+1)*1024;    // 32 keys * 32 d
            kf0n = *(const bf16x8*)(kpp);
            kf1n = *(const bf16x8*)(kpp + 16);
            const __bf16* vpp = vp + (i+1)*32;
            vf0n = *(const bf16x8*)(vpp);
            vf1n = *(const bf16x8*)(vpp + 16);
        }
        __builtin_amdgcn_sched_barrier(0);   // pin next-step load issue here

        // --- S^T = K * Q^T over 32 keys x 32 q, d=32 ---
        f32x16 s;
        #pragma unroll
        for (int r = 0; r < 16; ++r) s[r] = 0.f;
        __builtin_amdgcn_s_setprio(1);
        s = __builtin_amdgcn_mfma_f32_32x32x16_bf16(kf0, qf0, s, 0, 0, 0);
        s = __builtin_amdgcn_mfma_f32_32x32x16_bf16(kf1, qf1, s, 0, 0, 0);
        __builtin_amdgcn_s_setprio(0);

        // lane holds P[q=lo5][key = base + i*32 + (r&3)+8*(r>>2)+4*hi]
        float p[16];
        #pragma unroll
        for (int r = 0; r < 16; ++r) p[r] = fexp2(s[r]);
        float l0 = 0.f, l1 = 0.f;
        #pragma unroll
        for (int r = 0; r < 8; ++r) { l0 += p[r]; l1 += p[r+8]; }
        lsum += l0 + l1;

        unsigned a0 = cvtpk_bf16(p[0],  p[1]),  a1 = cvtpk_bf16(p[2],  p[3]);
        unsigned b0 = cvtpk_bf16(p[4],  p[5]),  b1 = cvtpk_bf16(p[6],  p[7]);
        unsigned c0 = cvtpk_bf16(p[8],  p[9]),  c1 = cvtpk_bf16(p[10], p[11]);
        unsigned d0 = cvtpk_bf16(p[12], p[13]), d1 = cvtpk_bf16(p[14], p[15]);
        asm("v_permlane32_swap_b32 %0, %1" : "+v"(a0), "+v"(b0));
        asm("v_permlane32_swap_b32 %0, %1" : "+v"(a1), "+v"(b1));
        asm("v_permlane32_swap_b32 %0, %1" : "+v"(c0), "+v"(d0));
        asm("v_permlane32_swap_b32 %0, %1" : "+v"(c1), "+v"(d1));
        union { bf16x8 v; unsigned u[4]; } f0, f1;
        f0.u[0] = a0; f0.u[1] = a1; f0.u[2] = b0; f0.u[3] = b1;
        f1.u[0] = c0; f1.u[1] = c1; f1.u[2] = d0; f1.u[3] = d1;

        __builtin_amdgcn_s_setprio(1);
        if (i & 1) {
            oaccB = __builtin_amdgcn_mfma_f32_32x32x16_bf16(f0.v, vf0, oaccB, 0, 0, 0);
            oaccB = __builtin_amdgcn_mfma_f32_32x32x16_bf16(f1.v, vf1, oaccB, 0, 0, 0);
        } else {
            oaccA = __builtin_amdgcn_mfma_f32_32x32x16_bf16(f0.v, vf0, oaccA, 0, 0, 0);
            oaccA = __builtin_amdgcn_mfma_f32_32x32x16_bf16(f1.v, vf1, oaccA, 0, 0, 0);
        }
        __builtin_amdgcn_s_setprio(0);
    }

    // combine hi-halves of lsum: both halves then hold full partial for q=lo5
    lsum += __shfl_xor(lsum, 32);

    f32x16 oa;
    #pragma unroll
    for (int r = 0; r < 16; ++r) oa[r] = oaccA[r] + oaccB[r];

    // split-1 waves publish partials; split-0 waves combine + write.
    if (swv == 1) {
        #pragma unroll
        for (int r = 0; r < 16; ++r) lds_o[qw][r][lane] = oa[r];
        lds_l[qw][lane] = lsum;
    }
    __syncthreads();
    if (swv == 0) {
        float lother = lds_l[qw][lane];
        float inv = 1.0f / (lsum + lother - 63.0f);   // lane lo5: inv for its q
        #pragma unroll
        for (int r = 0; r < 16; ++r) {
            float ov = oa[r] + lds_o[qw][r][lane];
            int qrw = (r & 3) + 8*(r >> 2) + 4*hi;
            float li = __shfl(inv, qrw);
            int q = q0 + qw*32 + qrw;
            if (q < N_)
                o[((size_t)b*N_ + q)*C_ + h*HD_ + lo5] = (__bf16)(ov * li);
        }
    }
}

// ---------------------------------------------------------------------------
// feat3: LDS 32x32 tile transpose (fp32). grid (54, 8, 4).
// ---------------------------------------------------------------------------
__global__ __launch_bounds__(256) void feat3(
    const float* __restrict__ y, float* __restrict__ outf)
{
    __shared__ float tl[32][33];
    int p0 = blockIdx.x*32, c0 = blockIdx.y*32, b = blockIdx.z;
    int cc = threadIdx.x & 31, rr = threadIdx.x >> 5;
    for (int i = rr; i < 32; i += 8)
        tl[i][cc] = y[((size_t)(b*N_) + 1 + p0 + i)*C_ + c0 + cc];
    __syncthreads();
    for (int i = rr; i < 32; i += 8)
        outf[((size_t)(b*C_) + c0 + i)*P_ + p0 + cc] = tl[cc][i];
}

// ---------------------------------------------------------------------------
extern "C" void kernel_launch(void* const* d_in, const int* in_sizes, int n_in,
                              void* d_out, int out_size, void* d_ws, size_t ws_size,
                              hipStream_t stream)
{
    const float* x        = (const float*)d_in[0];
    const float* W_pe     = (const float*)d_in[1];
    const float* b_pe     = (const float*)d_in[2];
    const float* cls_tok  = (const float*)d_in[3];
    const float* ln1_g    = (const float*)d_in[4];
    const float* ln1_b    = (const float*)d_in[5];
    const float* Wqkv     = (const float*)d_in[6];
    const float* Wproj    = (const float*)d_in[7];
    const float* bproj    = (const float*)d_in[8];
    const float* ln2_g    = (const float*)d_in[9];
    const float* ln2_b    = (const float*)d_in[10];
    const float* W1       = (const float*)d_in[11];
    const float* b1       = (const float*)d_in[12];
    const float* W2       = (const float*)d_in[13];
    const float* b2       = (const float*)d_in[14];
    const float* normf_g  = (const float*)d_in[15];
    const float* normf_b  = (const float*)d_in[16];

    const size_t MC = (size_t)M_*C_;    // 1,770,496
    float*  ws  = (float*)d_ws;
    float*  t   = ws;                               // MC fp32
    float*  yf  = ws + MC;                          // MC fp32 (final ln out)
    __bf16* ybf = (__bf16*)(ws + 2*MC);             // MC bf16
    __bf16* hbf = (__bf16*)(ws + 2*MC + MC/2);      // MC bf16
    __bf16* obf = (__bf16*)(ws + 2*MC + MC);        // MC bf16
    __bf16* wT  = (__bf16*)(ws + 2*MC + 3*(MC/2));  // 786432 bf16
    __bf16* qB  = wT + 2*768*256 + 6*256*256;       // [32][NPAD][32]
    __bf16* kB  = qB + (size_t)B_*NH_*NPAD*32;
    __bf16* vB  = kB + (size_t)B_*NH_*NPAD*32;      // [32][32][NPAD]

    __bf16* projT = wT + 2*768*256;
    __bf16* w1T   = projT + 2*256*256;
    __bf16* w2T   = w1T   + 2*256*256;

    float* out_cls  = (float*)d_out;
    float* out_feat = out_cls + B_*C_;

    wprep2<<<dim3(24, 8, 8), 256, 0, stream>>>(Wqkv, Wproj, W1, W2, wT);
    padzero<<<252, 256, 0, stream>>>(kB, vB);
    embed2<<<(B_*N_*C_)/256, 256, 0, stream>>>(x, W_pe, b_pe, cls_tok, t);

    const int GRID_M = (M_ + 63) / 64;   // 109
    for (int i = 0; i < 2; ++i) {
        ln4<<<M_/4, 256, 0, stream>>>(t, ybf, ln1_g + i*C_, ln1_b + i*C_);
        gemm_qkv4<<<dim3(GRID_M, 12), 256, 0, stream>>>(
            ybf, wT + (size_t)i*768*256, qB, kB, vB);
        attn15<<<dim3(32, 28), 256, 0, stream>>>(qB, kB, vB, obf);
        gemm4<256,true,false,true,false><<<dim3(GRID_M, 4), 256, 0, stream>>>(
            obf, projT + (size_t)i*65536, bproj + i*C_, t, nullptr);
        ln4<<<M_/4, 256, 0, stream>>>(t, ybf, ln2_g + i*C_, ln2_b + i*C_);
        gemm4<256,false,true,true,true><<<dim3(GRID_M, 4), 256, 0, stream>>>(
            ybf, w1T + (size_t)i*65536, b1 + i*C_, nullptr, hbf);
        gemm4<256,true,false,true,false><<<dim3(GRID_M, 4), 256, 0, stream>>>(
            hbf, w2T + (size_t)i*65536, b2 + i*C_, t, nullptr);
    }

    ln4f<<<M_/4, 256, 0, stream>>>(t, yf, normf_g, normf_b, out_cls);
    feat3<<<dim3(54, 8, 4), 256, 0, stream>>>(yf, out_feat);
}